// Round 1
// baseline (126.586 us; speedup 1.0000x reference)
//
#include <hip/hip_runtime.h>

// Reprojection multi-rig model.
// out[i] = intrs[cam]*(p_cam.xy/p_cam.z) + pps[cam] - points_2d[i]
// where p_cam = R(q)*points_3d[pi] + t,
//       q = rel_q (x) ref_q,  t = rel_t + R(rel_q)*ref_t
// Quaternions stored [x,y,z,w]; rotation p + 2*(w*(v x p) + v x (v x p)).

__global__ __launch_bounds__(256) void reproj_kernel(
    const float2* __restrict__ points_2d,
    const int*    __restrict__ camera_indices,
    const int2*   __restrict__ grouping_indices,
    const int*    __restrict__ point_indices,
    const float*  __restrict__ camera_pps,
    const float*  __restrict__ intrs,
    const float*  __restrict__ points_3d,
    const float*  __restrict__ ref_poses,
    const float*  __restrict__ rel_poses,
    float2*       __restrict__ out,
    int n)
{
    // Tiny read-only tables -> LDS (broadcast reads, avoids per-lane scatter to L1)
    __shared__ float s_rel[56];   // 8 rel poses x 7
    __shared__ float s_pps[16];   // 8 cams x 2
    __shared__ float s_intr[16];  // 8 cams x 2
    int tid = threadIdx.x;
    if (tid < 56) s_rel[tid] = rel_poses[tid];
    if (tid < 16) { s_pps[tid] = camera_pps[tid]; s_intr[tid] = intrs[tid]; }
    __syncthreads();

    int i = blockIdx.x * blockDim.x + tid;
    if (i >= n) return;

    // Coalesced streaming loads
    int2  gm  = grouping_indices[i];
    int   pi  = point_indices[i];
    int   cam = camera_indices[i];
    float2 p2d = points_2d[i];

    // ref pose gather (280 KB table, L2-resident)
    const float* rp = ref_poses + 7 * gm.x;
    float rtx = rp[0], rty = rp[1], rtz = rp[2];
    float rqx = rp[3], rqy = rp[4], rqz = rp[5], rqw = rp[6];

    // rel pose from LDS
    const float* lp = s_rel + 7 * gm.y;
    float ltx = lp[0], lty = lp[1], ltz = lp[2];
    float lqx = lp[3], lqy = lp[4], lqz = lp[5], lqw = lp[6];

    // t = rel_t + quat_rotate(rel_q, ref_t)
    float uvx = lqy * rtz - lqz * rty;
    float uvy = lqz * rtx - lqx * rtz;
    float uvz = lqx * rty - lqy * rtx;
    float uuvx = lqy * uvz - lqz * uvy;
    float uuvy = lqz * uvx - lqx * uvz;
    float uuvz = lqx * uvy - lqy * uvx;
    float tx = ltx + rtx + 2.0f * (lqw * uvx + uuvx);
    float ty = lty + rty + 2.0f * (lqw * uvy + uuvy);
    float tz = ltz + rtz + 2.0f * (lqw * uvz + uuvz);

    // q = quat_mul(rel_q, ref_q): w = w1*w2 - dot(v1,v2); v = w1*v2 + w2*v1 + v1 x v2
    float qw = lqw * rqw - (lqx * rqx + lqy * rqy + lqz * rqz);
    float qx = lqw * rqx + rqw * lqx + (lqy * rqz - lqz * rqy);
    float qy = lqw * rqy + rqw * lqy + (lqz * rqx - lqx * rqz);
    float qz = lqw * rqz + rqw * lqz + (lqx * rqy - lqy * rqx);

    // 3D point gather (6 MB table, L2/L3-resident). 12B stride -> 3 scalar loads.
    const float* pp = points_3d + 3 * pi;
    float px = pp[0], py = pp[1], pz = pp[2];

    // p_cam = quat_rotate(q, p) + t
    float v2x = qy * pz - qz * py;
    float v2y = qz * px - qx * pz;
    float v2z = qx * py - qy * px;
    float w2x = qy * v2z - qz * v2y;
    float w2y = qz * v2x - qx * v2z;
    float w2z = qx * v2y - qy * v2x;
    float pcx = px + 2.0f * (qw * v2x + w2x) + tx;
    float pcy = py + 2.0f * (qw * v2y + w2y) + ty;
    float pcz = pz + 2.0f * (qw * v2z + w2z) + tz;

    float invz = 1.0f / pcz;  // IEEE divide for numpy-matching accuracy
    float ux = s_intr[2 * cam]     * (pcx * invz) + s_pps[2 * cam];
    float uy = s_intr[2 * cam + 1] * (pcy * invz) + s_pps[2 * cam + 1];

    out[i] = make_float2(ux - p2d.x, uy - p2d.y);
}

extern "C" void kernel_launch(void* const* d_in, const int* in_sizes, int n_in,
                              void* d_out, int out_size, void* d_ws, size_t ws_size,
                              hipStream_t stream) {
    const float2* points_2d       = (const float2*)d_in[0];
    const int*    camera_indices  = (const int*)d_in[1];
    const int2*   grouping        = (const int2*)d_in[2];
    const int*    point_indices   = (const int*)d_in[3];
    const float*  camera_pps      = (const float*)d_in[4];
    const float*  intrs           = (const float*)d_in[5];
    const float*  points_3d       = (const float*)d_in[6];
    const float*  ref_poses       = (const float*)d_in[7];
    const float*  rel_poses       = (const float*)d_in[8];
    float2*       out             = (float2*)d_out;

    int n = in_sizes[1];  // N observations (camera_indices is (N,))
    int blocks = (n + 255) / 256;
    reproj_kernel<<<blocks, 256, 0, stream>>>(
        points_2d, camera_indices, grouping, point_indices,
        camera_pps, intrs, points_3d, ref_poses, rel_poses, out, n);
}